// Round 3
// baseline (368.065 us; speedup 1.0000x reference)
//
#include <hip/hip_runtime.h>
#include <hip/hip_bf16.h>
#include <hip/hip_fp16.h>

typedef _Float16 f16;
typedef _Float16 f16x4 __attribute__((ext_vector_type(4)));
typedef _Float16 f16x8 __attribute__((ext_vector_type(8)));
typedef float f32x4 __attribute__((ext_vector_type(4)));

#define MFMA16(a, b, c) __builtin_amdgcn_mfma_f32_16x16x32_f16(a, b, c, 0, 0, 0)

__device__ __forceinline__ float fexp2(float x) {
#if __has_builtin(__builtin_amdgcn_exp2f)
    return __builtin_amdgcn_exp2f(x);
#else
    return exp2f(x);
#endif
}

// ---------------- prep: f32 -> f16 convert ----------------
__global__ void k_convert_x(const float* __restrict__ in, f16* __restrict__ out, int n4) {
    int i = blockIdx.x * blockDim.x + threadIdx.x;
    if (i >= n4) return;
    float4 v = ((const float4*)in)[i];
    f16x4 o = {(f16)v.x, (f16)v.y, (f16)v.z, (f16)v.w};
    ((f16x4*)out)[i] = o;
}

// ---------------- prep: transpose f32[K][N] -> f16[N][K] ----------------
__global__ __launch_bounds__(256) void k_transpose(const float* __restrict__ in,
                                                   f16* __restrict__ out, int K, int N) {
    __shared__ f16 tile[64][72];
    int n0 = blockIdx.x * 64, k0 = blockIdx.y * 64;
    int t = threadIdx.x;
    int r = t >> 2, cb = (t & 3) * 16;
    const float* src = in + (size_t)(k0 + r) * N + n0 + cb;
#pragma unroll
    for (int j = 0; j < 4; ++j) {
        float4 v = ((const float4*)src)[j];
        tile[r][cb + 4 * j + 0] = (f16)v.x;
        tile[r][cb + 4 * j + 1] = (f16)v.y;
        tile[r][cb + 4 * j + 2] = (f16)v.z;
        tile[r][cb + 4 * j + 3] = (f16)v.w;
    }
    __syncthreads();
    int nl = t >> 2, kb = (t & 3) * 16;
    f16* dst = out + (size_t)(n0 + nl) * K + k0 + kb;
#pragma unroll
    for (int j = 0; j < 2; ++j) {
        f16x8 o;
#pragma unroll
        for (int e = 0; e < 8; ++e) o[e] = tile[kb + 8 * j + e][nl];
        *(f16x8*)(dst + 8 * j) = o;
    }
}

// ---------------- shared GEMM core: C(128x128) += A[M][768] * Bt[N][768]^T ----------------
__device__ __forceinline__ void gemm_core(const f16* __restrict__ A, const f16* __restrict__ Bt,
                                          int m0, int n0, int t, int lane, int wr, int wc,
                                          f16* As, f16* Bs, f32x4 acc[4][4]) {
    for (int kt = 0; kt < 24; ++kt) {
#pragma unroll
        for (int i = 0; i < 2; ++i) {
            int c = t + i * 256;
            int row = c >> 2, cb = (c & 3) * 8;
            f16x8 va = *(const f16x8*)(A + (size_t)(m0 + row) * 768 + kt * 32 + cb);
            f16x8 vb = *(const f16x8*)(Bt + (size_t)(n0 + row) * 768 + kt * 32 + cb);
            *(f16x8*)(As + row * 40 + cb) = va;
            *(f16x8*)(Bs + row * 40 + cb) = vb;
        }
        __syncthreads();
        f16x8 a[4], b[4];
#pragma unroll
        for (int i = 0; i < 4; ++i)
            a[i] = *(const f16x8*)(As + (wr * 64 + i * 16 + (lane & 15)) * 40 + (lane >> 4) * 8);
#pragma unroll
        for (int j = 0; j < 4; ++j)
            b[j] = *(const f16x8*)(Bs + (wc * 64 + j * 16 + (lane & 15)) * 40 + (lane >> 4) * 8);
#pragma unroll
        for (int i = 0; i < 4; ++i)
#pragma unroll
            for (int j = 0; j < 4; ++j) acc[i][j] = MFMA16(a[i], b[j], acc[i][j]);
        __syncthreads();
    }
}

// ---------------- QKV GEMM: xh[4096][768] x wqkv_t[2304][768]^T + bias -> Qh,Kh,Vt ----------------
__global__ __launch_bounds__(256) void k_qkv_gemm(const f16* __restrict__ A, const f16* __restrict__ Bt,
                                                  const float* __restrict__ bias,
                                                  f16* __restrict__ Qh, f16* __restrict__ Kh,
                                                  f16* __restrict__ Vt) {
    __shared__ f16 As[128 * 40];
    __shared__ f16 Bs[128 * 40];
    int m0 = blockIdx.x * 128, n0 = blockIdx.y * 128;
    int t = threadIdx.x, lane = t & 63, w = t >> 6;
    int wr = w >> 1, wc = w & 1;
    f32x4 zero = {0.f, 0.f, 0.f, 0.f};
    f32x4 acc[4][4];
#pragma unroll
    for (int i = 0; i < 4; ++i)
#pragma unroll
        for (int j = 0; j < 4; ++j) acc[i][j] = zero;

    gemm_core(A, Bt, m0, n0, t, lane, wr, wc, As, Bs, acc);

    // Q prescale folds softmax scale AND log2(e) so attention can use exp2:
    // 0.125 * 1.4426950408889634 = 0.18033688011112042
    const float QSCALE = 0.18033688011112042f;
#pragma unroll
    for (int j = 0; j < 4; ++j) {
        int n = n0 + wc * 64 + j * 16 + (lane & 15);
        int which = n / 768;
        int rem = n - which * 768;
        int h = rem >> 6, d = rem & 63;
        float bv = bias[n];
#pragma unroll
        for (int i = 0; i < 4; ++i) {
            int m = m0 + wr * 64 + i * 16 + ((lane >> 4) << 2);
            int bb = m >> 11, tt = m & 2047;
            int bh = bb * 12 + h;
            if (which == 2) {
                f16x4 pk;
#pragma unroll
                for (int r = 0; r < 4; ++r) pk[r] = (f16)(acc[i][j][r] + bv);
                *(f16x4*)(Vt + ((size_t)bh * 64 + d) * 2048 + tt) = pk;
            } else if (which == 0) {
#pragma unroll
                for (int r = 0; r < 4; ++r)
                    Qh[((size_t)bh * 2048 + tt + r) * 64 + d] = (f16)((acc[i][j][r] + bv) * QSCALE);
            } else {
#pragma unroll
                for (int r = 0; r < 4; ++r)
                    Kh[((size_t)bh * 2048 + tt + r) * 64 + d] = (f16)(acc[i][j][r] + bv);
            }
        }
    }
}

// ---------------- O GEMM: valh[4096][768] x wo_t[768][768]^T + bias -> out fp32 ----------------
__global__ __launch_bounds__(256) void k_o_gemm(const f16* __restrict__ A, const f16* __restrict__ Bt,
                                                const float* __restrict__ bias,
                                                float* __restrict__ out) {
    __shared__ f16 As[128 * 40];
    __shared__ f16 Bs[128 * 40];
    int m0 = blockIdx.x * 128, n0 = blockIdx.y * 128;
    int t = threadIdx.x, lane = t & 63, w = t >> 6;
    int wr = w >> 1, wc = w & 1;
    f32x4 zero = {0.f, 0.f, 0.f, 0.f};
    f32x4 acc[4][4];
#pragma unroll
    for (int i = 0; i < 4; ++i)
#pragma unroll
        for (int j = 0; j < 4; ++j) acc[i][j] = zero;

    gemm_core(A, Bt, m0, n0, t, lane, wr, wc, As, Bs, acc);

#pragma unroll
    for (int j = 0; j < 4; ++j) {
        int n = n0 + wc * 64 + j * 16 + (lane & 15);
        float bv = bias[n];
#pragma unroll
        for (int i = 0; i < 4; ++i) {
            int m = m0 + wr * 64 + i * 16 + ((lane >> 4) << 2);
#pragma unroll
            for (int r = 0; r < 4; ++r) out[(size_t)(m + r) * 768 + n] = acc[i][j][r] + bv;
        }
    }
}

// ---------------- attention: barrier-free, direct global fragment loads ----------------
// grid = 768 blocks (1D), XCD-swizzled so each XCD owns 3 heads (K/V L2-resident).
// Block = 4 waves; wave w owns 16 q-rows. Pass 1: lsum = rowsum(exp2(S')).
// Pass 2: recompute S', P = exp2(S')*linv -> fp32 attention store + per-wave LDS
// stage (f16) -> PV MFMA. No __syncthreads anywhere.
// P slice stride = 72 f16 (>= 64 k-values + pad). Round-2 bug was stride 40:
// rows overlapped -> corrupted P. Keep >= 64 always.
__global__ __launch_bounds__(256) void k_attn(const f16* __restrict__ Qh, const f16* __restrict__ Kh,
                                              const f16* __restrict__ Vt, float* __restrict__ attn,
                                              f16* __restrict__ valh) {
    __shared__ f16 Ps_all[4 * 16 * 72];
    int orig = blockIdx.x;
    int swz = (orig & 7) * 96 + (orig >> 3);   // 768 blocks, 8 XCDs, bijective
    int bh = swz >> 5, qt = swz & 31;
    int q0 = qt * 64;
    int t = threadIdx.x, lane = t & 63, w = t >> 6;

    const f16* qbase = Qh + ((size_t)bh * 2048 + q0 + w * 16) * 64;
    const f16* kbase = Kh + (size_t)bh * 2048 * 64;
    const f16* vbase = Vt + (size_t)bh * 64 * 2048;

    // Q fragments straight from global (row = lane&15, k-chunk = lane>>4)
    f16x8 aq[2];
#pragma unroll
    for (int f = 0; f < 2; ++f)
        aq[f] = *(const f16x8*)(qbase + (size_t)(lane & 15) * 64 + f * 32 + (lane >> 4) * 8);

    f32x4 zero = {0.f, 0.f, 0.f, 0.f};

    // ---- pass 1: row sums of exp2(S') ----
    float lsum[4] = {0.f, 0.f, 0.f, 0.f};
#pragma unroll 2
    for (int kt = 0; kt < 32; ++kt) {
        const f16* kp = kbase + (size_t)kt * 64 * 64;
#pragma unroll
        for (int s = 0; s < 4; ++s) {
            const f16* krow = kp + (size_t)(s * 16 + (lane & 15)) * 64 + (lane >> 4) * 8;
            f16x8 b0 = *(const f16x8*)(krow);
            f16x8 b1 = *(const f16x8*)(krow + 32);
            f32x4 sacc = MFMA16(aq[0], b0, zero);
            sacc = MFMA16(aq[1], b1, sacc);
#pragma unroll
            for (int r = 0; r < 4; ++r) lsum[r] += fexp2(sacc[r]);
        }
    }
#pragma unroll
    for (int r = 0; r < 4; ++r) {
#pragma unroll
        for (int off = 1; off < 16; off <<= 1) lsum[r] += __shfl_xor(lsum[r], off, 64);
    }
    float linv[4];
#pragma unroll
    for (int r = 0; r < 4; ++r) linv[r] = 1.0f / lsum[r];

    // ---- pass 2: P write + PV ----
    f32x4 accv[4];
#pragma unroll
    for (int j = 0; j < 4; ++j) accv[j] = zero;
    f16* Ps = Ps_all + w * 16 * 72;   // wave-private slice: no barriers needed
    float* attn_base = attn + ((size_t)bh * 2048 + q0 + w * 16) * 2048;

    for (int kt = 0; kt < 32; ++kt) {
        const f16* kp = kbase + (size_t)kt * 64 * 64;
#pragma unroll
        for (int s = 0; s < 4; ++s) {
            const f16* krow = kp + (size_t)(s * 16 + (lane & 15)) * 64 + (lane >> 4) * 8;
            f16x8 b0 = *(const f16x8*)(krow);
            f16x8 b1 = *(const f16x8*)(krow + 32);
            f32x4 sacc = MFMA16(aq[0], b0, zero);
            sacc = MFMA16(aq[1], b1, sacc);
#pragma unroll
            for (int r = 0; r < 4; ++r) {
                float p = fexp2(sacc[r]) * linv[r];
                attn_base[(size_t)((lane >> 4) * 4 + r) * 2048 + kt * 64 + s * 16 + (lane & 15)] = p;
                Ps[((lane >> 4) * 4 + r) * 72 + s * 16 + (lane & 15)] = (f16)p;
            }
        }
        // PV: A = P[16q][64k] (Ps, wave-private), B = V from global (Vt is [d][t])
        f16x8 pa[2];
#pragma unroll
        for (int c2 = 0; c2 < 2; ++c2)
            pa[c2] = *(const f16x8*)(Ps + (lane & 15) * 72 + c2 * 32 + (lane >> 4) * 8);
        const f16* vp = vbase + kt * 64;
#pragma unroll
        for (int j = 0; j < 4; ++j) {
#pragma unroll
            for (int c2 = 0; c2 < 2; ++c2) {
                f16x8 bv = *(const f16x8*)(vp + (size_t)(j * 16 + (lane & 15)) * 2048 + c2 * 32 + (lane >> 4) * 8);
                accv[j] = MFMA16(pa[c2], bv, accv[j]);
            }
        }
    }

    // epilogue: values -> valh [b*2048+t][h*64+d] f16
    int b = bh / 12, h = bh - b * 12;
#pragma unroll
    for (int j = 0; j < 4; ++j) {
#pragma unroll
        for (int r = 0; r < 4; ++r) {
            int rowg = b * 2048 + q0 + w * 16 + (lane >> 4) * 4 + r;
            int col = h * 64 + j * 16 + (lane & 15);
            valh[(size_t)rowg * 768 + col] = (f16)accv[j][r];
        }
    }
}

extern "C" void kernel_launch(void* const* d_in, const int* in_sizes, int n_in,
                              void* d_out, int out_size, void* d_ws, size_t ws_size,
                              hipStream_t stream) {
    const float* x = (const float*)d_in[0];
    const float* wqkv = (const float*)d_in[1];
    const float* bqkv = (const float*)d_in[2];
    const float* wo = (const float*)d_in[3];
    const float* bo = (const float*)d_in[4];

    float* out_o = (float*)d_out;                          // [2,2048,768] fp32
    float* out_attn = out_o + (size_t)2 * 2048 * 768;      // [2,12,2048,2048] fp32

    f16* ws = (f16*)d_ws;
    f16* xh = ws;                       // 3,145,728
    f16* wqkv_t = xh + 3145728;         // 1,769,472  [2304][768]
    f16* wo_t = wqkv_t + 1769472;       // 589,824    [768][768]
    f16* Qh = wo_t + 589824;            // [bh][t][64], pre-scaled by 0.125*log2(e)
    f16* Kh = Qh + 3145728;             // [bh][t][64]
    f16* Vt = Kh + 3145728;             // [bh][64][t]  (transposed)
    f16* valh = Vt + 3145728;           // [4096][768]

    k_convert_x<<<3072, 256, 0, stream>>>(x, xh, 786432);
    k_transpose<<<dim3(36, 12), 256, 0, stream>>>(wqkv, wqkv_t, 768, 2304);
    k_transpose<<<dim3(12, 12), 256, 0, stream>>>(wo, wo_t, 768, 768);
    k_qkv_gemm<<<dim3(32, 18), 256, 0, stream>>>(xh, wqkv_t, bqkv, Qh, Kh, Vt);
    k_attn<<<768, 256, 0, stream>>>(Qh, Kh, Vt, out_attn, valh);
    k_o_gemm<<<dim3(32, 6), 256, 0, stream>>>(valh, wo_t, bo, out_o);
}

// Round 5
// 345.504 us; speedup vs baseline: 1.0653x; 1.0653x over previous
//
#include <hip/hip_runtime.h>
#include <hip/hip_bf16.h>
#include <hip/hip_fp16.h>

typedef _Float16 f16;
typedef _Float16 f16x4 __attribute__((ext_vector_type(4)));
typedef _Float16 f16x8 __attribute__((ext_vector_type(8)));
typedef float f32x4 __attribute__((ext_vector_type(4)));

#define MFMA16(a, b, c) __builtin_amdgcn_mfma_f32_16x16x32_f16(a, b, c, 0, 0, 0)

__device__ __forceinline__ float fexp2(float x) {
#if __has_builtin(__builtin_amdgcn_exp2f)
    return __builtin_amdgcn_exp2f(x);
#else
    return exp2f(x);
#endif
}

// ---------------- prep: f32 -> f16 convert ----------------
__global__ void k_convert_x(const float* __restrict__ in, f16* __restrict__ out, int n4) {
    int i = blockIdx.x * blockDim.x + threadIdx.x;
    if (i >= n4) return;
    float4 v = ((const float4*)in)[i];
    f16x4 o = {(f16)v.x, (f16)v.y, (f16)v.z, (f16)v.w};
    ((f16x4*)out)[i] = o;
}

// ---------------- prep: transpose f32[K][N] -> f16[N][K] ----------------
__global__ __launch_bounds__(256) void k_transpose(const float* __restrict__ in,
                                                   f16* __restrict__ out, int K, int N) {
    __shared__ f16 tile[64][72];
    int n0 = blockIdx.x * 64, k0 = blockIdx.y * 64;
    int t = threadIdx.x;
    int r = t >> 2, cb = (t & 3) * 16;
    const float* src = in + (size_t)(k0 + r) * N + n0 + cb;
#pragma unroll
    for (int j = 0; j < 4; ++j) {
        float4 v = ((const float4*)src)[j];
        tile[r][cb + 4 * j + 0] = (f16)v.x;
        tile[r][cb + 4 * j + 1] = (f16)v.y;
        tile[r][cb + 4 * j + 2] = (f16)v.z;
        tile[r][cb + 4 * j + 3] = (f16)v.w;
    }
    __syncthreads();
    int nl = t >> 2, kb = (t & 3) * 16;
    f16* dst = out + (size_t)(n0 + nl) * K + k0 + kb;
#pragma unroll
    for (int j = 0; j < 2; ++j) {
        f16x8 o;
#pragma unroll
        for (int e = 0; e < 8; ++e) o[e] = tile[kb + 8 * j + e][nl];
        *(f16x8*)(dst + 8 * j) = o;
    }
}

// ---------------- shared GEMM core: C(128x128) += A[M][768] * Bt[N][768]^T ----------------
__device__ __forceinline__ void gemm_core(const f16* __restrict__ A, const f16* __restrict__ Bt,
                                          int m0, int n0, int t, int lane, int wr, int wc,
                                          f16* As, f16* Bs, f32x4 acc[4][4]) {
    for (int kt = 0; kt < 24; ++kt) {
#pragma unroll
        for (int i = 0; i < 2; ++i) {
            int c = t + i * 256;
            int row = c >> 2, cb = (c & 3) * 8;
            f16x8 va = *(const f16x8*)(A + (size_t)(m0 + row) * 768 + kt * 32 + cb);
            f16x8 vb = *(const f16x8*)(Bt + (size_t)(n0 + row) * 768 + kt * 32 + cb);
            *(f16x8*)(As + row * 40 + cb) = va;
            *(f16x8*)(Bs + row * 40 + cb) = vb;
        }
        __syncthreads();
        f16x8 a[4], b[4];
#pragma unroll
        for (int i = 0; i < 4; ++i)
            a[i] = *(const f16x8*)(As + (wr * 64 + i * 16 + (lane & 15)) * 40 + (lane >> 4) * 8);
#pragma unroll
        for (int j = 0; j < 4; ++j)
            b[j] = *(const f16x8*)(Bs + (wc * 64 + j * 16 + (lane & 15)) * 40 + (lane >> 4) * 8);
#pragma unroll
        for (int i = 0; i < 4; ++i)
#pragma unroll
            for (int j = 0; j < 4; ++j) acc[i][j] = MFMA16(a[i], b[j], acc[i][j]);
        __syncthreads();
    }
}

// ---------------- QKV GEMM: xh[4096][768] x wqkv_t[2304][768]^T + bias -> Qh,Kh,Vt ----------------
__global__ __launch_bounds__(256) void k_qkv_gemm(const f16* __restrict__ A, const f16* __restrict__ Bt,
                                                  const float* __restrict__ bias,
                                                  f16* __restrict__ Qh, f16* __restrict__ Kh,
                                                  f16* __restrict__ Vt) {
    __shared__ f16 As[128 * 40];
    __shared__ f16 Bs[128 * 40];
    int m0 = blockIdx.x * 128, n0 = blockIdx.y * 128;
    int t = threadIdx.x, lane = t & 63, w = t >> 6;
    int wr = w >> 1, wc = w & 1;
    f32x4 zero = {0.f, 0.f, 0.f, 0.f};
    f32x4 acc[4][4];
#pragma unroll
    for (int i = 0; i < 4; ++i)
#pragma unroll
        for (int j = 0; j < 4; ++j) acc[i][j] = zero;

    gemm_core(A, Bt, m0, n0, t, lane, wr, wc, As, Bs, acc);

    // Q prescale folds softmax scale AND log2(e) so attention can use exp2:
    // 0.125 * 1.4426950408889634 = 0.18033688011112042
    const float QSCALE = 0.18033688011112042f;
#pragma unroll
    for (int j = 0; j < 4; ++j) {
        int n = n0 + wc * 64 + j * 16 + (lane & 15);
        int which = n / 768;
        int rem = n - which * 768;
        int h = rem >> 6, d = rem & 63;
        float bv = bias[n];
#pragma unroll
        for (int i = 0; i < 4; ++i) {
            int m = m0 + wr * 64 + i * 16 + ((lane >> 4) << 2);
            int bb = m >> 11, tt = m & 2047;
            int bh = bb * 12 + h;
            if (which == 2) {
                f16x4 pk;
#pragma unroll
                for (int r = 0; r < 4; ++r) pk[r] = (f16)(acc[i][j][r] + bv);
                *(f16x4*)(Vt + ((size_t)bh * 64 + d) * 2048 + tt) = pk;
            } else if (which == 0) {
#pragma unroll
                for (int r = 0; r < 4; ++r)
                    Qh[((size_t)bh * 2048 + tt + r) * 64 + d] = (f16)((acc[i][j][r] + bv) * QSCALE);
            } else {
#pragma unroll
                for (int r = 0; r < 4; ++r)
                    Kh[((size_t)bh * 2048 + tt + r) * 64 + d] = (f16)(acc[i][j][r] + bv);
            }
        }
    }
}

// ---------------- O GEMM: valh[4096][768] x wo_t[768][768]^T + bias -> out fp32 ----------------
__global__ __launch_bounds__(256) void k_o_gemm(const f16* __restrict__ A, const f16* __restrict__ Bt,
                                                const float* __restrict__ bias,
                                                float* __restrict__ out) {
    __shared__ f16 As[128 * 40];
    __shared__ f16 Bs[128 * 40];
    int m0 = blockIdx.x * 128, n0 = blockIdx.y * 128;
    int t = threadIdx.x, lane = t & 63, w = t >> 6;
    int wr = w >> 1, wc = w & 1;
    f32x4 zero = {0.f, 0.f, 0.f, 0.f};
    f32x4 acc[4][4];
#pragma unroll
    for (int i = 0; i < 4; ++i)
#pragma unroll
        for (int j = 0; j < 4; ++j) acc[i][j] = zero;

    gemm_core(A, Bt, m0, n0, t, lane, wr, wc, As, Bs, acc);

#pragma unroll
    for (int j = 0; j < 4; ++j) {
        int n = n0 + wc * 64 + j * 16 + (lane & 15);
        float bv = bias[n];
#pragma unroll
        for (int i = 0; i < 4; ++i) {
            int m = m0 + wr * 64 + i * 16 + ((lane >> 4) << 2);
#pragma unroll
            for (int r = 0; r < 4; ++r) out[(size_t)(m + r) * 768 + n] = acc[i][j][r] + bv;
        }
    }
}

// ---------------- attention: barrier-free + register-prefetch pipeline ----------------
// grid = 768 blocks, XCD-swizzled. 4 waves/block, wave = 16 q-rows, no __syncthreads.
// Round-3 lesson (vmcnt shares loads+stores): all global LOADS for an iteration are
// issued BEFORE the attn stores, so waiting on load data never drains the 400 MB
// store stream. K double-buffered in registers (prefetch depth 1); V loaded at
// iteration top; attn stores are nontemporal (never re-read; keep L2 for K/V).
__global__ __launch_bounds__(256) void k_attn(const f16* __restrict__ Qh, const f16* __restrict__ Kh,
                                              const f16* __restrict__ Vt, float* __restrict__ attn,
                                              f16* __restrict__ valh) {
    __shared__ __align__(16) f16 Ps_all[4 * 16 * 72];
    int orig = blockIdx.x;
    int swz = (orig & 7) * 96 + (orig >> 3);   // 768 blocks, 8 XCDs, bijective
    int bh = swz >> 5, qt = swz & 31;
    int q0 = qt * 64;
    int t = threadIdx.x, lane = t & 63, w = t >> 6;

    const f16* qbase = Qh + ((size_t)bh * 2048 + q0 + w * 16) * 64;
    const f16* kbase = Kh + (size_t)bh * 2048 * 64;
    const f16* vbase = Vt + (size_t)bh * 64 * 2048;

    f16x8 aq[2];
#pragma unroll
    for (int f = 0; f < 2; ++f)
        aq[f] = *(const f16x8*)(qbase + (size_t)(lane & 15) * 64 + f * 32 + (lane >> 4) * 8);

    f32x4 zero = {0.f, 0.f, 0.f, 0.f};

    auto LOADK = [&](f16x8* dst, int kt) {
        const f16* kp = kbase + (size_t)kt * 4096;
#pragma unroll
        for (int s = 0; s < 4; ++s) {
            const f16* krow = kp + (size_t)(s * 16 + (lane & 15)) * 64 + (lane >> 4) * 8;
            dst[2 * s] = *(const f16x8*)(krow);
            dst[2 * s + 1] = *(const f16x8*)(krow + 32);
        }
    };
    auto QKT = [&](const f16x8* kf, f32x4* s4) {
#pragma unroll
        for (int s = 0; s < 4; ++s) {
            s4[s] = MFMA16(aq[0], kf[2 * s], zero);
            s4[s] = MFMA16(aq[1], kf[2 * s + 1], s4[s]);
        }
    };

    f16x8 ka[8], kb2[8];

    // ---- pass 1: row sums of exp2(S'), K prefetched one tile ahead ----
    float lsum[4] = {0.f, 0.f, 0.f, 0.f};
    LOADK(ka, 0);
    for (int kt = 0; kt < 32; kt += 2) {
        f32x4 s4[4];
        LOADK(kb2, kt + 1);
        QKT(ka, s4);
#pragma unroll
        for (int s = 0; s < 4; ++s)
#pragma unroll
            for (int r = 0; r < 4; ++r) lsum[r] += fexp2(s4[s][r]);
        LOADK(ka, (kt + 2) & 31);
        QKT(kb2, s4);
#pragma unroll
        for (int s = 0; s < 4; ++s)
#pragma unroll
            for (int r = 0; r < 4; ++r) lsum[r] += fexp2(s4[s][r]);
    }
#pragma unroll
    for (int r = 0; r < 4; ++r) {
#pragma unroll
        for (int off = 1; off < 16; off <<= 1) lsum[r] += __shfl_xor(lsum[r], off, 64);
    }
    float linv[4];
#pragma unroll
    for (int r = 0; r < 4; ++r) linv[r] = 1.0f / lsum[r];

    // ---- pass 2: loads-first pipeline ----
    f32x4 accv[4];
#pragma unroll
    for (int j = 0; j < 4; ++j) accv[j] = zero;
    f16* Ps = Ps_all + w * 16 * 72;   // wave-private slice
    float* attn_base = attn + ((size_t)bh * 2048 + q0 + w * 16) * 2048;
    f16x8 vbuf[8];

    auto step2 = [&](f16x8* curK, f16x8* nxtK, int kt) {
        // 1) all loads first: next K tile + this tile's V (before any store)
        LOADK(nxtK, (kt + 1) & 31);
        {
            const f16* vp = vbase + kt * 64;
#pragma unroll
            for (int j = 0; j < 4; ++j) {
                const f16* vrow = vp + (size_t)(j * 16 + (lane & 15)) * 2048 + (lane >> 4) * 8;
                vbuf[2 * j] = *(const f16x8*)(vrow);
                vbuf[2 * j + 1] = *(const f16x8*)(vrow + 32);
            }
        }
        // 2) QK^T with current K (waits only on loads issued last iteration)
        f32x4 s4[4];
        QKT(curK, s4);
        // 3) softmax + stores (nontemporal; never waited on)
        float* ab = attn_base + kt * 64;
#pragma unroll
        for (int s = 0; s < 4; ++s) {
#pragma unroll
            for (int r = 0; r < 4; ++r) {
                float p = fexp2(s4[s][r]) * linv[r];
                __builtin_nontemporal_store(
                    p, ab + (size_t)((lane >> 4) * 4 + r) * 2048 + s * 16 + (lane & 15));
                Ps[((lane >> 4) * 4 + r) * 72 + s * 16 + (lane & 15)] = (f16)p;
            }
        }
        // 4) P fragment from wave-private LDS
        f16x8 pa[2];
#pragma unroll
        for (int c2 = 0; c2 < 2; ++c2)
            pa[c2] = *(const f16x8*)(Ps + (lane & 15) * 72 + c2 * 32 + (lane >> 4) * 8);
        // 5) PV with V loaded at step 1 (wait allows the stores to stay outstanding)
#pragma unroll
        for (int j = 0; j < 4; ++j) {
            accv[j] = MFMA16(pa[0], vbuf[2 * j], accv[j]);
            accv[j] = MFMA16(pa[1], vbuf[2 * j + 1], accv[j]);
        }
    };

    LOADK(ka, 0);
    for (int kt = 0; kt < 32; kt += 2) {
        step2(ka, kb2, kt);
        step2(kb2, ka, kt + 1);
    }

    // epilogue: values -> valh [b*2048+t][h*64+d] f16
    int b = bh / 12, h = bh - b * 12;
#pragma unroll
    for (int j = 0; j < 4; ++j) {
#pragma unroll
        for (int r = 0; r < 4; ++r) {
            int rowg = b * 2048 + q0 + w * 16 + (lane >> 4) * 4 + r;
            int col = h * 64 + j * 16 + (lane & 15);
            valh[(size_t)rowg * 768 + col] = (f16)accv[j][r];
        }
    }
}

extern "C" void kernel_launch(void* const* d_in, const int* in_sizes, int n_in,
                              void* d_out, int out_size, void* d_ws, size_t ws_size,
                              hipStream_t stream) {
    const float* x = (const float*)d_in[0];
    const float* wqkv = (const float*)d_in[1];
    const float* bqkv = (const float*)d_in[2];
    const float* wo = (const float*)d_in[3];
    const float* bo = (const float*)d_in[4];

    float* out_o = (float*)d_out;                          // [2,2048,768] fp32
    float* out_attn = out_o + (size_t)2 * 2048 * 768;      // [2,12,2048,2048] fp32

    f16* ws = (f16*)d_ws;
    f16* xh = ws;                       // 3,145,728
    f16* wqkv_t = xh + 3145728;         // 1,769,472  [2304][768]
    f16* wo_t = wqkv_t + 1769472;       // 589,824    [768][768]
    f16* Qh = wo_t + 589824;            // [bh][t][64], pre-scaled by 0.125*log2(e)
    f16* Kh = Qh + 3145728;             // [bh][t][64]
    f16* Vt = Kh + 3145728;             // [bh][64][t]  (transposed)
    f16* valh = Vt + 3145728;           // [4096][768]

    k_convert_x<<<3072, 256, 0, stream>>>(x, xh, 786432);
    k_transpose<<<dim3(36, 12), 256, 0, stream>>>(wqkv, wqkv_t, 768, 2304);
    k_transpose<<<dim3(12, 12), 256, 0, stream>>>(wo, wo_t, 768, 768);
    k_qkv_gemm<<<dim3(32, 18), 256, 0, stream>>>(xh, wqkv_t, bqkv, Qh, Kh, Vt);
    k_attn<<<768, 256, 0, stream>>>(Qh, Kh, Vt, out_attn, valh);
    k_o_gemm<<<dim3(32, 6), 256, 0, stream>>>(valh, wo_t, bo, out_o);
}

// Round 6
// 200.736 us; speedup vs baseline: 1.8336x; 1.7212x over previous
//
#include <hip/hip_runtime.h>
#include <hip/hip_bf16.h>
#include <hip/hip_fp16.h>

typedef _Float16 f16;
typedef _Float16 f16x4 __attribute__((ext_vector_type(4)));
typedef _Float16 f16x8 __attribute__((ext_vector_type(8)));
typedef float f32x4 __attribute__((ext_vector_type(4)));

#define MFMA16(a, b, c) __builtin_amdgcn_mfma_f32_16x16x32_f16(a, b, c, 0, 0, 0)

__device__ __forceinline__ float fexp2(float x) {
#if __has_builtin(__builtin_amdgcn_exp2f)
    return __builtin_amdgcn_exp2f(x);
#else
    return exp2f(x);
#endif
}

// ---------------- prep: f32 -> f16 convert ----------------
__global__ void k_convert_x(const float* __restrict__ in, f16* __restrict__ out, int n4) {
    int i = blockIdx.x * blockDim.x + threadIdx.x;
    if (i >= n4) return;
    float4 v = ((const float4*)in)[i];
    f16x4 o = {(f16)v.x, (f16)v.y, (f16)v.z, (f16)v.w};
    ((f16x4*)out)[i] = o;
}

// ---------------- prep: transpose f32[K][N] -> f16[N][K] ----------------
__global__ __launch_bounds__(256) void k_transpose(const float* __restrict__ in,
                                                   f16* __restrict__ out, int K, int N) {
    __shared__ f16 tile[64][72];
    int n0 = blockIdx.x * 64, k0 = blockIdx.y * 64;
    int t = threadIdx.x;
    int r = t >> 2, cb = (t & 3) * 16;
    const float* src = in + (size_t)(k0 + r) * N + n0 + cb;
#pragma unroll
    for (int j = 0; j < 4; ++j) {
        float4 v = ((const float4*)src)[j];
        tile[r][cb + 4 * j + 0] = (f16)v.x;
        tile[r][cb + 4 * j + 1] = (f16)v.y;
        tile[r][cb + 4 * j + 2] = (f16)v.z;
        tile[r][cb + 4 * j + 3] = (f16)v.w;
    }
    __syncthreads();
    int nl = t >> 2, kb = (t & 3) * 16;
    f16* dst = out + (size_t)(n0 + nl) * K + k0 + kb;
#pragma unroll
    for (int j = 0; j < 2; ++j) {
        f16x8 o;
#pragma unroll
        for (int e = 0; e < 8; ++e) o[e] = tile[kb + 8 * j + e][nl];
        *(f16x8*)(dst + 8 * j) = o;
    }
}

// ---------------- shared GEMM core: C(128x128) += A[M][768] * Bt[N][768]^T ----------------
__device__ __forceinline__ void gemm_core(const f16* __restrict__ A, const f16* __restrict__ Bt,
                                          int m0, int n0, int t, int lane, int wr, int wc,
                                          f16* As, f16* Bs, f32x4 acc[4][4]) {
    for (int kt = 0; kt < 24; ++kt) {
#pragma unroll
        for (int i = 0; i < 2; ++i) {
            int c = t + i * 256;
            int row = c >> 2, cb = (c & 3) * 8;
            f16x8 va = *(const f16x8*)(A + (size_t)(m0 + row) * 768 + kt * 32 + cb);
            f16x8 vb = *(const f16x8*)(Bt + (size_t)(n0 + row) * 768 + kt * 32 + cb);
            *(f16x8*)(As + row * 40 + cb) = va;
            *(f16x8*)(Bs + row * 40 + cb) = vb;
        }
        __syncthreads();
        f16x8 a[4], b[4];
#pragma unroll
        for (int i = 0; i < 4; ++i)
            a[i] = *(const f16x8*)(As + (wr * 64 + i * 16 + (lane & 15)) * 40 + (lane >> 4) * 8);
#pragma unroll
        for (int j = 0; j < 4; ++j)
            b[j] = *(const f16x8*)(Bs + (wc * 64 + j * 16 + (lane & 15)) * 40 + (lane >> 4) * 8);
#pragma unroll
        for (int i = 0; i < 4; ++i)
#pragma unroll
            for (int j = 0; j < 4; ++j) acc[i][j] = MFMA16(a[i], b[j], acc[i][j]);
        __syncthreads();
    }
}

// ---------------- QKV GEMM -> Qh (row layout), Kf/Vf (MFMA-fragment-linear layouts) ----------------
// Kf: element (bh, kt, f=s*2+half, lane=hi*16+lo, e) = K[token=kt*64+s*16+lo][d=half*32+hi*8+e]
// Vf: element (bh, kt, f=jd*2+half, lane=hi*16+lo, e) = V[token=kt*64+half*32+hi*8+e][d=jd*16+lo]
// so that k_attn's per-wave fragment loads are 1KB fully-contiguous dwordx4.
__global__ __launch_bounds__(256) void k_qkv_gemm(const f16* __restrict__ A, const f16* __restrict__ Bt,
                                                  const float* __restrict__ bias,
                                                  f16* __restrict__ Qh, f16* __restrict__ Kf,
                                                  f16* __restrict__ Vf) {
    __shared__ f16 As[128 * 40];
    __shared__ f16 Bs[128 * 40];
    int m0 = blockIdx.x * 128, n0 = blockIdx.y * 128;
    int t = threadIdx.x, lane = t & 63, w = t >> 6;
    int wr = w >> 1, wc = w & 1;
    f32x4 zero = {0.f, 0.f, 0.f, 0.f};
    f32x4 acc[4][4];
#pragma unroll
    for (int i = 0; i < 4; ++i)
#pragma unroll
        for (int j = 0; j < 4; ++j) acc[i][j] = zero;

    gemm_core(A, Bt, m0, n0, t, lane, wr, wc, As, Bs, acc);

    // Q prescale folds softmax scale AND log2(e): 0.125 * log2(e)
    const float QSCALE = 0.18033688011112042f;
#pragma unroll
    for (int j = 0; j < 4; ++j) {
        int n = n0 + wc * 64 + j * 16 + (lane & 15);
        int which = n / 768;
        int rem = n - which * 768;
        int h = rem >> 6, d = rem & 63;
        float bv = bias[n];
#pragma unroll
        for (int i = 0; i < 4; ++i) {
            int m = m0 + wr * 64 + i * 16 + ((lane >> 4) << 2);
            int bb = m >> 11, tt = m & 2047;
            int bh = bb * 12 + h;
            if (which == 2) {
                // V fragment layout (vectorizable along r -> e)
                int kt = tt >> 6;
                int half = (tt & 63) >> 5, hi = (tt & 31) >> 3, e0 = tt & 7;
                int jd = d >> 4, lo = d & 15;
                size_t addr = (((size_t)bh * 32 + kt) * 8 + jd * 2 + half) * 512 +
                              (size_t)(hi * 16 + lo) * 8 + e0;
                f16x4 pk;
#pragma unroll
                for (int r = 0; r < 4; ++r) pk[r] = (f16)(acc[i][j][r] + bv);
                *(f16x4*)(Vf + addr) = pk;
            } else if (which == 0) {
#pragma unroll
                for (int r = 0; r < 4; ++r)
                    Qh[((size_t)bh * 2048 + tt + r) * 64 + d] = (f16)((acc[i][j][r] + bv) * QSCALE);
            } else {
                // K fragment layout (scalar along r -> lo)
                int half = d >> 5, hi = (d & 31) >> 3, e = d & 7;
#pragma unroll
                for (int r = 0; r < 4; ++r) {
                    int tr = tt + r;
                    int kt = tr >> 6, row = tr & 63;
                    int s = row >> 4, lo = row & 15;
                    size_t addr = (((size_t)bh * 32 + kt) * 8 + s * 2 + half) * 512 +
                                  (size_t)(hi * 16 + lo) * 8 + e;
                    Kf[addr] = (f16)(acc[i][j][r] + bv);
                }
            }
        }
    }
}

// ---------------- O GEMM: valh[4096][768] x wo_t[768][768]^T + bias -> out fp32 ----------------
__global__ __launch_bounds__(256) void k_o_gemm(const f16* __restrict__ A, const f16* __restrict__ Bt,
                                                const float* __restrict__ bias,
                                                float* __restrict__ out) {
    __shared__ f16 As[128 * 40];
    __shared__ f16 Bs[128 * 40];
    int m0 = blockIdx.x * 128, n0 = blockIdx.y * 128;
    int t = threadIdx.x, lane = t & 63, w = t >> 6;
    int wr = w >> 1, wc = w & 1;
    f32x4 zero = {0.f, 0.f, 0.f, 0.f};
    f32x4 acc[4][4];
#pragma unroll
    for (int i = 0; i < 4; ++i)
#pragma unroll
        for (int j = 0; j < 4; ++j) acc[i][j] = zero;

    gemm_core(A, Bt, m0, n0, t, lane, wr, wc, As, Bs, acc);

#pragma unroll
    for (int j = 0; j < 4; ++j) {
        int n = n0 + wc * 64 + j * 16 + (lane & 15);
        float bv = bias[n];
#pragma unroll
        for (int i = 0; i < 4; ++i) {
            int m = m0 + wr * 64 + i * 16 + ((lane >> 4) << 2);
#pragma unroll
            for (int r = 0; r < 4; ++r) out[(size_t)(m + r) * 768 + n] = acc[i][j][r] + bv;
        }
    }
}

// ---------------- attention: contiguous fragment loads + LDS-transposed coalesced stores ----------------
// grid = 768 blocks, XCD-swizzled; 4 waves/block, wave = 16 q-rows; no __syncthreads.
// All K/V loads are 1KB contiguous (fragment-linear layout). P staged f32 in wave-private
// LDS (stride 68 = 16B-aligned rows, <=2-way banks on store path), then:
//   - 4x dwordx4 coalesced global stores (256B runs) for the attention output
//   - PV A-fragment rebuilt as f16 from the same tile.
// Per-iteration VMEM order: [8 V][8 K-next][4 stores] so waiting on V (vmcnt<=12)
// or prev-K (vmcnt<=20) never forces store retirement.
__global__ __launch_bounds__(256, 3) void k_attn(const f16* __restrict__ Qh, const f16* __restrict__ Kf,
                                                 const f16* __restrict__ Vf, float* __restrict__ attn,
                                                 f16* __restrict__ valh) {
    __shared__ __align__(16) float Ps32_all[4][16 * 68];
    int orig = blockIdx.x;
    int swz = (orig & 7) * 96 + (orig >> 3);   // 768 blocks, 8 XCDs, bijective
    int bh = swz >> 5, qt = swz & 31;
    int q0 = qt * 64;
    int t = threadIdx.x, lane = t & 63, w = t >> 6;

    const f16* qbase = Qh + ((size_t)bh * 2048 + q0 + w * 16) * 64;
    const f16* kfb = Kf + (size_t)bh * 32 * 4096 + (size_t)lane * 8;
    const f16* vfb = Vf + (size_t)bh * 32 * 4096 + (size_t)lane * 8;

    f16x8 aq[2];
#pragma unroll
    for (int f = 0; f < 2; ++f)
        aq[f] = *(const f16x8*)(qbase + (size_t)(lane & 15) * 64 + f * 32 + (lane >> 4) * 8);

    f32x4 zero = {0.f, 0.f, 0.f, 0.f};

    auto LOADK = [&](f16x8* dst, int kt) {
        const f16* kp = kfb + (size_t)kt * 4096;
#pragma unroll
        for (int f = 0; f < 8; ++f) dst[f] = *(const f16x8*)(kp + f * 512);
    };
    auto LOADV = [&](f16x8* dst, int kt) {
        const f16* vp = vfb + (size_t)kt * 4096;
#pragma unroll
        for (int f = 0; f < 8; ++f) dst[f] = *(const f16x8*)(vp + f * 512);
    };
    auto QKT = [&](const f16x8* kf, f32x4* s4) {
#pragma unroll
        for (int s = 0; s < 4; ++s) {
            s4[s] = MFMA16(aq[0], kf[2 * s], zero);
            s4[s] = MFMA16(aq[1], kf[2 * s + 1], s4[s]);
        }
    };

    f16x8 ka[8], kb2[8];

    // ---- pass 1: row sums of exp2(S'), K prefetched one tile ahead ----
    float lsum[4] = {0.f, 0.f, 0.f, 0.f};
    LOADK(ka, 0);
    for (int kt = 0; kt < 32; kt += 2) {
        f32x4 s4[4];
        LOADK(kb2, kt + 1);
        QKT(ka, s4);
#pragma unroll
        for (int s = 0; s < 4; ++s)
#pragma unroll
            for (int r = 0; r < 4; ++r) lsum[r] += fexp2(s4[s][r]);
        LOADK(ka, (kt + 2) & 31);
        QKT(kb2, s4);
#pragma unroll
        for (int s = 0; s < 4; ++s)
#pragma unroll
            for (int r = 0; r < 4; ++r) lsum[r] += fexp2(s4[s][r]);
    }
#pragma unroll
    for (int r = 0; r < 4; ++r) {
#pragma unroll
        for (int off = 1; off < 16; off <<= 1) lsum[r] += __shfl_xor(lsum[r], off, 64);
    }
    float linv[4];
#pragma unroll
    for (int r = 0; r < 4; ++r) linv[r] = 1.0f / lsum[r];

    // ---- pass 2 ----
    f32x4 accv[4];
#pragma unroll
    for (int j = 0; j < 4; ++j) accv[j] = zero;
    float* Ps = Ps32_all[w];   // wave-private 16 x 68 f32
    float* attn_base = attn + ((size_t)bh * 2048 + q0 + w * 16) * 2048;
    f16x8 vbuf[8];

    auto step2 = [&](f16x8* curK, f16x8* nxtK, int kt) {
        // 1) loads first: V (oldest), then next K
        LOADV(vbuf, kt);
        LOADK(nxtK, (kt + 1) & 31);
        // 2) QK^T with current K
        f32x4 s4[4];
        QKT(curK, s4);
        // 3) softmax -> wave-private f32 LDS tile [q][k], stride 68
#pragma unroll
        for (int s = 0; s < 4; ++s) {
#pragma unroll
            for (int r = 0; r < 4; ++r) {
                float p = fexp2(s4[s][r]) * linv[r];
                Ps[((lane >> 4) * 4 + r) * 68 + s * 16 + (lane & 15)] = p;
            }
        }
        // 4) PV A-fragment (f16) from the tile
        f16x8 pa[2];
#pragma unroll
        for (int half = 0; half < 2; ++half) {
            const float* pr = Ps + (lane & 15) * 68 + half * 32 + (lane >> 4) * 8;
            f32x4 lo = *(const f32x4*)(pr);
            f32x4 hi = *(const f32x4*)(pr + 4);
            f16x8 pf = {(f16)lo[0], (f16)lo[1], (f16)lo[2], (f16)lo[3],
                        (f16)hi[0], (f16)hi[1], (f16)hi[2], (f16)hi[3]};
            pa[half] = pf;
        }
        // 5) coalesced attention stores: 4x dwordx4, 256B runs per 16-lane group
        float* ab = attn_base + kt * 64;
#pragma unroll
        for (int i = 0; i < 4; ++i) {
            int row = i * 4 + (lane >> 4);
            int col = (lane & 15) * 4;
            f32x4 v = *(const f32x4*)(Ps + row * 68 + col);
            *(f32x4*)(ab + (size_t)row * 2048 + col) = v;
        }
        // 6) PV MFMA (waits vbuf: vmcnt<=12, stores stay outstanding)
#pragma unroll
        for (int jd = 0; jd < 4; ++jd) {
            accv[jd] = MFMA16(pa[0], vbuf[2 * jd], accv[jd]);
            accv[jd] = MFMA16(pa[1], vbuf[2 * jd + 1], accv[jd]);
        }
    };

    LOADK(ka, 0);
    for (int kt = 0; kt < 32; kt += 2) {
        step2(ka, kb2, kt);
        step2(kb2, ka, kt + 1);
    }

    // epilogue: values -> valh [b*2048+t][h*64+d] f16
    int b = bh / 12, h = bh - b * 12;
#pragma unroll
    for (int j = 0; j < 4; ++j) {
#pragma unroll
        for (int r = 0; r < 4; ++r) {
            int rowg = b * 2048 + q0 + w * 16 + (lane >> 4) * 4 + r;
            int col = h * 64 + j * 16 + (lane & 15);
            valh[(size_t)rowg * 768 + col] = (f16)accv[j][r];
        }
    }
}

extern "C" void kernel_launch(void* const* d_in, const int* in_sizes, int n_in,
                              void* d_out, int out_size, void* d_ws, size_t ws_size,
                              hipStream_t stream) {
    const float* x = (const float*)d_in[0];
    const float* wqkv = (const float*)d_in[1];
    const float* bqkv = (const float*)d_in[2];
    const float* wo = (const float*)d_in[3];
    const float* bo = (const float*)d_in[4];

    float* out_o = (float*)d_out;                          // [2,2048,768] fp32
    float* out_attn = out_o + (size_t)2 * 2048 * 768;      // [2,12,2048,2048] fp32

    f16* ws = (f16*)d_ws;
    f16* xh = ws;                       // 3,145,728
    f16* wqkv_t = xh + 3145728;         // 1,769,472  [2304][768]
    f16* wo_t = wqkv_t + 1769472;       // 589,824    [768][768]
    f16* Qh = wo_t + 589824;            // [bh][t][64], pre-scaled
    f16* Kf = Qh + 3145728;             // fragment-linear K
    f16* Vf = Kf + 3145728;             // fragment-linear V
    f16* valh = Vf + 3145728;           // [4096][768]

    k_convert_x<<<3072, 256, 0, stream>>>(x, xh, 786432);
    k_transpose<<<dim3(36, 12), 256, 0, stream>>>(wqkv, wqkv_t, 768, 2304);
    k_transpose<<<dim3(12, 12), 256, 0, stream>>>(wo, wo_t, 768, 768);
    k_qkv_gemm<<<dim3(32, 18), 256, 0, stream>>>(xh, wqkv_t, bqkv, Qh, Kf, Vf);
    k_attn<<<768, 256, 0, stream>>>(Qh, Kf, Vf, out_attn, valh);
    k_o_gemm<<<dim3(32, 6), 256, 0, stream>>>(valh, wo_t, bo, out_o);
}